// Round 1
// baseline (295.524 us; speedup 1.0000x reference)
//
#include <hip/hip_runtime.h>
#include <cstdint>
#include <cstddef>

// Dual attention (channel attention), B=16 S=512 D=1024 H=16 dk=64.
// Round 5: gemm3 was 77us at MfmaUtil 28% = the m97-class 2-barrier 128^2
// structure ceiling (aggravated by short K=1024). Ported the projection GEMM
// to the 256^2 8-phase template (T2 swizzle + T3/T4 counted vmcnt + T5
// setprio): 256x256 tile, BK=64 as two 32-wide k-half planes, 8 waves,
// 128KB double-buffered LDS. Counted vmcnt(4) twice per K-tile, never 0
// mid-loop. gemm_f16 (output proj) keeps the old proven body this round.
// Pipeline:
//   1. pack: f32 -> fp16 (q,k,v,Wq,Wk,Wv,Wo) + zero scores
//   2. gemm3_8ph (z=3): Pq16,Pk16 = f16(A@W^T+b) [f16 out]; Pv = f32 out
//   3. scores[b,i,j] = sum_{s,c} Pq16[b,s,64i+c]*Pk16[b,s,64j+c]  (MFMA)
//   4. softmax (x0.25 scale) -> attn (d_out tail); Mm = I + beta*attn
//   5. xmix[r,64i+c] = f16( sum_j Mm[i,j]*Pv[r,64j+c] )
//   6. out = f16 GEMM(xmix, Wo^T) + bo -> d_out
// mask (d_in[3]) and adj (d_in[4]) are unused by the reference.

#define DIM 1024

typedef _Float16 f16_t;
typedef _Float16 f16x4_t __attribute__((ext_vector_type(4)));
typedef _Float16 f16x8_t __attribute__((ext_vector_type(8)));
typedef float    f32x4_t __attribute__((ext_vector_type(4)));

__device__ __forceinline__ void async_ld16(const void* g, void* l) {
    __builtin_amdgcn_global_load_lds((const __attribute__((address_space(1))) void*)g,
                                     (__attribute__((address_space(3))) void*)l,
                                     16, 0, 0);
}

// ---------------------------------------------------------------- pack kernel
// float4 units: q 2097152 | k 2097152 | v 2097152 | Wq 262144 | Wk 262144
//               | Wv 262144 | Wo 262144 => 7340032 units. Tail 16 blocks zero
//               the 4096-float scores buffer. Grid 28688 blocks.
__global__ __launch_bounds__(256) void pack_kernel(
    const float* __restrict__ q, const float* __restrict__ k, const float* __restrict__ v,
    const float* __restrict__ Wq, const float* __restrict__ Wk,
    const float* __restrict__ Wv, const float* __restrict__ Wo,
    f16_t* __restrict__ Aq, f16_t* __restrict__ Ak, f16_t* __restrict__ Av,
    f16_t* __restrict__ Bq, f16_t* __restrict__ Bk,
    f16_t* __restrict__ Bv, f16_t* __restrict__ Bo,
    float* __restrict__ scores)
{
    const int u = blockIdx.x * 256 + threadIdx.x;
    if (u >= 7340032) {            // tail: zero scores accumulator
        scores[u - 7340032] = 0.f;
        return;
    }
    const float* src; f16_t* dst; int i;
    if (u < 2097152)      { src = q;  dst = Aq; i = u; }
    else if (u < 4194304) { src = k;  dst = Ak; i = u - 2097152; }
    else if (u < 6291456) { src = v;  dst = Av; i = u - 4194304; }
    else if (u < 6553600) { src = Wq; dst = Bq; i = u - 6291456; }
    else if (u < 6815744) { src = Wk; dst = Bk; i = u - 6553600; }
    else if (u < 7077888) { src = Wv; dst = Bv; i = u - 6815744; }
    else                  { src = Wo; dst = Bo; i = u - 7077888; }
    float4 s = ((const float4*)src)[i];
    f16x4_t h;
    h[0] = (f16_t)s.x; h[1] = (f16_t)s.y; h[2] = (f16_t)s.z; h[3] = (f16_t)s.w;
    ((f16x4_t*)dst)[i] = h;
}

// ------------------------------------------------ 256x256 8-phase GEMM body
// C[m,n] = sum_k A[m,k]*B[n,k] + bias[n]. A [M,1024] f16 rm, B [1024,1024]
// f16 rm (W [out,in] -> C = A@W^T). Tile 256x256, BK=64 split into two
// 32-wide k-half planes; 8 waves (2M x 4N), per-wave 128x64 out (8x4 frags).
// LDS 128KB: 2 buffers x {A,B} x 2 planes x 16KB.
// Plane layout: fused row-pairs (fr=row>>1, 128B each), 16B units
// XOR-swizzled: unit' = (((row&1)<<2)|ku) ^ (fr&7). Verified: frag
// ds_read_b128 lands 2 lanes/bank (free, m136) AND the linear
// global_load_lds destination order (thread t -> plane unit t) equals the
// read permutation (T21 both-sides rule).
// Schedule per K-tile: 4 phases {ds_read frags; issue 2 stage loads;
// barrier; setprio(1); 16 MFMA; setprio(0); barrier}. Counted vmcnt(4) at
// end of ph1 (A1B1(kt) landed) and ph3 (A0B0(kt+1) landed) only -- 4 loads
// always in flight, drains to 0 only at kt=15.
__device__ __forceinline__ void gemm256_body(
    const f16_t* __restrict__ A, const f16_t* __restrict__ Bm,
    const float* __restrict__ bias, float* __restrict__ C, f16_t* __restrict__ C16,
    f16_t* lds, int tileM, int tileN)
{
    const int tid  = threadIdx.x;
    const int lane = tid & 63;
    const int w    = tid >> 6;
    const int wm   = (w & 1) << 7;                 // 0 / 128
    const int wn   = (w >> 1) << 6;                // 0..192
    const int lr   = lane & 15;                    // frag row
    const int cu   = lane >> 4;                    // frag 16B k-unit
    const int up   = (((lr & 1) << 2) | cu) ^ (lr >> 1);   // swizzled unit
    const int abase = ((w & 1) << 12) + ((lr >> 1) << 6) + (up << 3); // elems
    const int bbase = ((w >> 1) << 11) + ((lr >> 1) << 6) + (up << 3);

    // staging constants: thread t writes plane 16B-unit (c*512 + t); the
    // global element it must carry is row = c*128 + (t>>3)*2 + (su>>2),
    // k-unit = su&3 with su = (t&7) ^ ((t>>3)&7).
    const int su   = (tid & 7) ^ ((tid >> 3) & 7);
    const int srow = ((tid >> 3) << 1) | (su >> 2);
    const int sk   = (su & 3) << 3;
    const f16_t* srcA = A  + (size_t)(tileM + srow) * DIM + sk;
    const f16_t* srcB = Bm + (size_t)(tileN + srow) * DIM + sk;
    f16_t* dstW = lds + (w << 9);                  // wave-uniform dest base

#define STG(mat, kk, c, kt, b)  async_ld16( \
        ((mat) ? srcB : srcA) + (size_t)(c) * 128 * DIM + (kt) * 64 + (kk) * 32, \
        dstW + (b) * 32768 + (mat) * 16384 + (kk) * 8192 + (c) * 4096)

    f32x4_t acc[8][4];
#pragma unroll
    for (int i = 0; i < 8; ++i)
#pragma unroll
        for (int j = 0; j < 4; ++j)
            acc[i][j] = (f32x4_t){0.f, 0.f, 0.f, 0.f};

    // prologue: K-tile 0 -> buffer 0. Issue order matters for vmcnt counts:
    // A0,B0 (kk=0) first, then A1,B1.
    STG(0,0,0, 0,0); STG(0,0,1, 0,0);
    STG(1,0,0, 0,0); STG(1,0,1, 0,0);
    STG(0,1,0, 0,0); STG(0,1,1, 0,0);
    STG(1,1,0, 0,0); STG(1,1,1, 0,0);
    asm volatile("s_waitcnt vmcnt(4)" ::: "memory");   // A0,B0 landed
    __builtin_amdgcn_s_barrier();
    __builtin_amdgcn_sched_barrier(0);

#pragma unroll 2
    for (int kt = 0; kt < 16; ++kt) {
        const int b  = kt & 1;
        const int nb = b ^ 1;
        const f16_t* Lb = lds + b * 32768;  // A0 @0, A1 @8192, B0 @16384, B1 @24576
        f16x8_t af[4], bf[4];

        // ---- phase 0: kk=0, m-frags 0-3 (+ all 4 B kk0 frags)
#pragma unroll
        for (int nt = 0; nt < 4; ++nt)
            bf[nt] = *(const f16x8_t*)(Lb + 16384 + bbase + (nt << 9));
#pragma unroll
        for (int mt = 0; mt < 4; ++mt)
            af[mt] = *(const f16x8_t*)(Lb + abase + (mt << 9));
        if (kt < 15) { STG(0,0,0, kt+1, nb); STG(0,0,1, kt+1, nb); }
        __builtin_amdgcn_s_barrier();
        __builtin_amdgcn_s_setprio(1);
#pragma unroll
        for (int mt = 0; mt < 4; ++mt)
#pragma unroll
            for (int nt = 0; nt < 4; ++nt)
                acc[mt][nt] = __builtin_amdgcn_mfma_f32_16x16x32_f16(
                    af[mt], bf[nt], acc[mt][nt], 0, 0, 0);
        __builtin_amdgcn_s_setprio(0);
        __builtin_amdgcn_s_barrier();

        // ---- phase 1: kk=0, m-frags 4-7 (B kk0 frags reused from regs)
#pragma unroll
        for (int mt = 0; mt < 4; ++mt)
            af[mt] = *(const f16x8_t*)(Lb + abase + ((mt + 4) << 9));
        if (kt < 15) { STG(1,0,0, kt+1, nb); STG(1,0,1, kt+1, nb); }
        __builtin_amdgcn_s_barrier();
        __builtin_amdgcn_s_setprio(1);
#pragma unroll
        for (int mt = 0; mt < 4; ++mt)
#pragma unroll
            for (int nt = 0; nt < 4; ++nt)
                acc[mt + 4][nt] = __builtin_amdgcn_mfma_f32_16x16x32_f16(
                    af[mt], bf[nt], acc[mt + 4][nt], 0, 0, 0);
        __builtin_amdgcn_s_setprio(0);
        // A1,B1 of kt landed (next 4 loads stay in flight); tail drains.
        if (kt < 15) asm volatile("s_waitcnt vmcnt(4)" ::: "memory");
        else         asm volatile("s_waitcnt vmcnt(0)" ::: "memory");
        __builtin_amdgcn_s_barrier();
        __builtin_amdgcn_sched_barrier(0);

        // ---- phase 2: kk=1, m-frags 0-3 (+ all 4 B kk1 frags)
#pragma unroll
        for (int nt = 0; nt < 4; ++nt)
            bf[nt] = *(const f16x8_t*)(Lb + 24576 + bbase + (nt << 9));
#pragma unroll
        for (int mt = 0; mt < 4; ++mt)
            af[mt] = *(const f16x8_t*)(Lb + 8192 + abase + (mt << 9));
        if (kt < 15) { STG(0,1,0, kt+1, nb); STG(0,1,1, kt+1, nb); }
        __builtin_amdgcn_s_barrier();
        __builtin_amdgcn_s_setprio(1);
#pragma unroll
        for (int mt = 0; mt < 4; ++mt)
#pragma unroll
            for (int nt = 0; nt < 4; ++nt)
                acc[mt][nt] = __builtin_amdgcn_mfma_f32_16x16x32_f16(
                    af[mt], bf[nt], acc[mt][nt], 0, 0, 0);
        __builtin_amdgcn_s_setprio(0);
        __builtin_amdgcn_s_barrier();

        // ---- phase 3: kk=1, m-frags 4-7
#pragma unroll
        for (int mt = 0; mt < 4; ++mt)
            af[mt] = *(const f16x8_t*)(Lb + 8192 + abase + ((mt + 4) << 9));
        if (kt < 15) { STG(1,1,0, kt+1, nb); STG(1,1,1, kt+1, nb); }
        __builtin_amdgcn_s_barrier();
        __builtin_amdgcn_s_setprio(1);
#pragma unroll
        for (int mt = 0; mt < 4; ++mt)
#pragma unroll
            for (int nt = 0; nt < 4; ++nt)
                acc[mt + 4][nt] = __builtin_amdgcn_mfma_f32_16x16x32_f16(
                    af[mt], bf[nt], acc[mt + 4][nt], 0, 0, 0);
        __builtin_amdgcn_s_setprio(0);
        // A0,B0 of kt+1 landed (A1,B1 of kt+1 stay in flight)
        if (kt < 15) asm volatile("s_waitcnt vmcnt(4)" ::: "memory");
        __builtin_amdgcn_s_barrier();
        __builtin_amdgcn_sched_barrier(0);
    }
#undef STG

    // epilogue. C/D layout: col = lane&15, row = (lane>>4)*4 + reg
    const int rq = (lane >> 4) << 2;
    if (C16) {
#pragma unroll
        for (int nt = 0; nt < 4; ++nt) {
            const int col = tileN + wn + (nt << 4) + lr;
            const float bv = bias[col];
#pragma unroll
            for (int mt = 0; mt < 8; ++mt) {
                const int row = tileM + wm + (mt << 4) + rq;
#pragma unroll
                for (int r = 0; r < 4; ++r)
                    C16[(size_t)(row + r) * DIM + col] = (f16_t)(acc[mt][nt][r] + bv);
            }
        }
    } else {
#pragma unroll
        for (int nt = 0; nt < 4; ++nt) {
            const int col = tileN + wn + (nt << 4) + lr;
            const float bv = bias[col];
#pragma unroll
            for (int mt = 0; mt < 8; ++mt) {
                const int row = tileM + wm + (mt << 4) + rq;
#pragma unroll
                for (int r = 0; r < 4; ++r)
                    C[(size_t)(row + r) * DIM + col] = acc[mt][nt][r] + bv;
            }
        }
    }
}

struct Gemm3Args {
    const f16_t* A[3];
    const f16_t* B[3];
    const float* bias[3];
    float*       C[3];    // z=2 (Pv) f32 out
    f16_t*       C16[3];  // z=0,1 (Pq16, Pk16) f16 out
};

// three projection GEMMs in one launch: grid (32, 4, 3), 512 threads
__global__ __launch_bounds__(512, 2) void gemm3_8ph(Gemm3Args args)
{
    __shared__ __align__(16) f16_t lds[65536];   // 128 KB
    const int z = blockIdx.z;
    gemm256_body(args.A[z], args.B[z], args.bias[z], args.C[z], args.C16[z],
                 lds, blockIdx.x * 256, blockIdx.y * 256);
}

// ---------------------------------------------------------------- old 128^2 GEMM
// kept (proven) for the output projection this round.
__device__ __forceinline__ void gemm_body(
    const f16_t* __restrict__ A, const f16_t* __restrict__ B,
    const float* __restrict__ bias, float* __restrict__ C, f16_t* __restrict__ C16,
    f16_t* As, f16_t* Bs, int tileM, int tileN)
{
    const int tid  = threadIdx.x;
    const int lane = tid & 63;
    const int w    = tid >> 6;
    const int wm = (w & 1) << 6;
    const int wn = (w >> 1) << 6;

    f32x4_t acc[4][4];
#pragma unroll
    for (int i = 0; i < 4; ++i)
#pragma unroll
        for (int j = 0; j < 4; ++j)
            acc[i][j] = (f32x4_t){0.f, 0.f, 0.f, 0.f};

    const int srow = lane >> 3;
    const int scol = ((lane & 7) ^ (lane >> 3)) << 3;
    const int arow = lane & 15;
    const int sx   = lane & 7;
    const int kqu  = lane >> 4;

    for (int kt = 0; kt < 16; ++kt) {
        const int k0 = kt << 6;
#pragma unroll
        for (int t = 0; t < 4; ++t) {
            const int row = (w << 5) + (t << 3);
            async_ld16(A + (size_t)(tileM + row + srow) * DIM + k0 + scol,
                       (void*)(As + row * 64));
            async_ld16(B + (size_t)(tileN + row + srow) * DIM + k0 + scol,
                       (void*)(Bs + row * 64));
        }
        __syncthreads();
#pragma unroll
        for (int kk = 0; kk < 2; ++kk) {
            const int cuv = ((kk << 2) + kqu) ^ sx;
            f16x8_t af[4], bfv[4];
#pragma unroll
            for (int mt = 0; mt < 4; ++mt)
                af[mt] = *(const f16x8_t*)(As + (wm + (mt << 4) + arow) * 64 + (cuv << 3));
#pragma unroll
            for (int nt = 0; nt < 4; ++nt)
                bfv[nt] = *(const f16x8_t*)(Bs + (wn + (nt << 4) + arow) * 64 + (cuv << 3));
#pragma unroll
            for (int mt = 0; mt < 4; ++mt)
#pragma unroll
                for (int nt = 0; nt < 4; ++nt)
                    acc[mt][nt] = __builtin_amdgcn_mfma_f32_16x16x32_f16(
                        af[mt], bfv[nt], acc[mt][nt], 0, 0, 0);
        }
        __syncthreads();
    }

    const int rq = (lane >> 4) << 2;
#pragma unroll
    for (int nt = 0; nt < 4; ++nt) {
        const int col = tileN + wn + (nt << 4) + arow;
        const float bv = bias[col];
#pragma unroll
        for (int mt = 0; mt < 4; ++mt) {
            const int row = tileM + wm + (mt << 4) + rq;
#pragma unroll
            for (int r = 0; r < 4; ++r)
                C[(size_t)(row + r) * DIM + col] = acc[mt][nt][r] + bv;
        }
    }
}

// single GEMM, f32 out (output projection)
__global__ __launch_bounds__(256) void gemm_f16(
    const f16_t* __restrict__ A, const f16_t* __restrict__ B,
    const float* __restrict__ bias, float* __restrict__ C)
{
    __shared__ __align__(16) f16_t As[128 * 64];
    __shared__ __align__(16) f16_t Bs[128 * 64];
    gemm_body(A, B, bias, C, nullptr, As, Bs, blockIdx.x * 128, blockIdx.y * 128);
}

// ---------------------------------------------------------------- scores
// scores[b,i,j] = sum_n Qf[b,i,n] Kf[b,j,n], n = s*64+c. MFMA 16x16x32 per
// 32-c chunk. Grid (16 batches, 32 slices); wave w owns s = slice*16+w*4..+3.
__global__ __launch_bounds__(256) void scores_kernel(
    const f16_t* __restrict__ Pq16, const f16_t* __restrict__ Pk16,
    float* __restrict__ scores)
{
    __shared__ float red[4][256];
    const int b = blockIdx.x;
    const int lane = threadIdx.x & 63;
    const int w = threadIdx.x >> 6;
    const int m  = lane & 15;
    const int q8 = (lane >> 4) << 3;

    f32x4_t acc = (f32x4_t){0.f, 0.f, 0.f, 0.f};
    const int s0 = blockIdx.y * 16 + w * 4;
#pragma unroll
    for (int ss = 0; ss < 4; ++ss) {
        const size_t rb = (size_t)(b * 512 + s0 + ss) * DIM;
        const f16_t* qrow = Pq16 + rb;
        const f16_t* krow = Pk16 + rb;
#pragma unroll
        for (int c0 = 0; c0 < 64; c0 += 32) {
            f16x8_t af = *(const f16x8_t*)(qrow + m * 64 + c0 + q8);
            f16x8_t bf = *(const f16x8_t*)(krow + m * 64 + c0 + q8);
            acc = __builtin_amdgcn_mfma_f32_16x16x32_f16(af, bf, acc, 0, 0, 0);
        }
    }
    const int rq = (lane >> 4) << 2;
#pragma unroll
    for (int r = 0; r < 4; ++r)
        red[w][(rq + r) * 16 + m] = acc[r];
    __syncthreads();
    const int t = threadIdx.x;
    const float sum = red[0][t] + red[1][t] + red[2][t] + red[3][t];
    atomicAdd(&scores[b * 256 + t], sum);
}

// ---------------------------------------------------------------- softmax
__global__ __launch_bounds__(256) void softmax_kernel(
    const float* __restrict__ scores, const float* __restrict__ beta_p,
    float* __restrict__ attn_out, float* __restrict__ Mm)
{
    const int t = threadIdx.x;
    const int i = t & 15;
    const float beta = beta_p[0];
    float s[16];
    float mx = -1e30f;
#pragma unroll
    for (int j = 0; j < 16; ++j) {
        s[j] = scores[t * 16 + j] * 0.25f;
        mx = fmaxf(mx, s[j]);
    }
    float sum = 0.f;
#pragma unroll
    for (int j = 0; j < 16; ++j) { s[j] = expf(s[j] - mx); sum += s[j]; }
    const float inv = 1.f / sum;
#pragma unroll
    for (int j = 0; j < 16; ++j) {
        float a = s[j] * inv;
        attn_out[t * 16 + j] = a;
        Mm[t * 16 + j] = beta * a + ((j == i) ? 1.f : 0.f);
    }
}

// ---------------------------------------------------------------- channel mix
__global__ __launch_bounds__(256) void mix_kernel(
    const float* __restrict__ Pv, const float* __restrict__ Mm,
    f16_t* __restrict__ xmix)
{
    __shared__ float Msh[256];
    const int rbase = blockIdx.x * 8;
    const int b = rbase >> 9;
    Msh[threadIdx.x] = Mm[b * 256 + threadIdx.x];
    __syncthreads();
    const int w = threadIdx.x >> 6;
    const int lane = threadIdx.x & 63;
#pragma unroll
    for (int rr = 0; rr < 2; ++rr) {
        const int r = rbase + w * 2 + rr;
        const float* vrow = Pv + (size_t)r * DIM;
        float v[16];
#pragma unroll
        for (int j = 0; j < 16; ++j) v[j] = vrow[j * 64 + lane];
#pragma unroll
        for (int i = 0; i < 16; ++i) {
            float x = 0.f;
#pragma unroll
            for (int j = 0; j < 16; ++j) x += Msh[i * 16 + j] * v[j];
            xmix[(size_t)r * DIM + i * 64 + lane] = (f16_t)x;
        }
    }
}

// ---------------------------------------------------------------- launch
extern "C" void kernel_launch(void* const* d_in, const int* in_sizes, int n_in,
                              void* d_out, int out_size, void* d_ws, size_t ws_size,
                              hipStream_t stream)
{
    (void)in_sizes; (void)n_in; (void)out_size; (void)ws_size;
    const float* q    = (const float*)d_in[0];
    const float* k    = (const float*)d_in[1];
    const float* v    = (const float*)d_in[2];
    // d_in[3] mask, d_in[4] adj: unused by reference
    const float* Wq   = (const float*)d_in[5];
    const float* bq   = (const float*)d_in[6];
    const float* Wk   = (const float*)d_in[7];
    const float* bk   = (const float*)d_in[8];
    const float* Wv   = (const float*)d_in[9];
    const float* bv   = (const float*)d_in[10];
    const float* Wo   = (const float*)d_in[11];
    const float* bo   = (const float*)d_in[12];
    const float* beta = (const float*)d_in[13];

    float* out  = (float*)d_out;                     // [8192,1024]
    float* attn = (float*)d_out + 8388608;           // [16,16,16]

    char* p = (char*)d_ws;
    auto take = [&](size_t n) -> char* {
        char* cur = p; p += (n + 255) & ~(size_t)255; return cur;
    };
    f16_t* Aq = (f16_t*)take(16777216);
    f16_t* Ak = (f16_t*)take(16777216);
    f16_t* Av = (f16_t*)take(16777216);
    f16_t* Bq = (f16_t*)take(2097152);
    f16_t* Bk = (f16_t*)take(2097152);
    f16_t* Bv = (f16_t*)take(2097152);
    f16_t* Bo = (f16_t*)take(2097152);
    f16_t* Pq16 = (f16_t*)take(16777216);
    f16_t* Pk16 = (f16_t*)take(16777216);
    float* Pv = (float*)take(33554432);
    float* scores = (float*)take(16384);
    float* Mm     = (float*)take(16384);
    f16_t* xmix = Aq;  // Aq dead after gemm3; reuse for xmix

    pack_kernel<<<28688, 256, 0, stream>>>(q, k, v, Wq, Wk, Wv, Wo,
                                           Aq, Ak, Av, Bq, Bk, Bv, Bo, scores);

    Gemm3Args ga;
    ga.A[0] = Aq; ga.A[1] = Ak; ga.A[2] = Av;
    ga.B[0] = Bq; ga.B[1] = Bk; ga.B[2] = Bv;
    ga.bias[0] = bq; ga.bias[1] = bk; ga.bias[2] = bv;
    ga.C[0] = nullptr; ga.C[1] = nullptr; ga.C[2] = Pv;
    ga.C16[0] = Pq16; ga.C16[1] = Pk16; ga.C16[2] = nullptr;
    gemm3_8ph<<<dim3(32, 4, 3), 512, 0, stream>>>(ga);

    scores_kernel<<<dim3(16, 32), 256, 0, stream>>>(Pq16, Pk16, scores);
    softmax_kernel<<<1, 256, 0, stream>>>(scores, beta, attn, Mm);
    mix_kernel<<<1024, 256, 0, stream>>>(Pv, Mm, xmix);
    gemm_f16<<<dim3(64, 8), 256, 0, stream>>>(xmix, Bo, bo, out);
}

// Round 2
// 289.761 us; speedup vs baseline: 1.0199x; 1.0199x over previous
//
#include <hip/hip_runtime.h>
#include <cstdint>
#include <cstddef>

// Dual attention (channel attention), B=16 S=512 D=1024 H=16 dk=64.
// Round 6: R5's 256^2 8-phase port regressed (92us, MfmaUtil 22%, VALUBusy
// 10%): (a) 384 blocks @ 1 block/CU = 2 rounds (1.5 needed) -> 33% idle;
// (b) per-phase ~1000cy stalls = compiler-inserted vmcnt(0) before ds_reads
// (single shared array + runtime offsets -> may-alias with in-flight DMA).
// R6: BM=256 BN=128 BK=32, grid (32,8,3)=768 = exactly 3 rounds; FOUR
// distinct __shared__ buffer objects per matrix (guaranteed no-alias for
// the waitcnt pass); prefetch depth 3 (tiles kt+1..kt+3 in flight, 6-9
// loads), ONE {vmcnt(6); s_barrier} per K-tile, never drained mid-loop.
// Same body drives the output projection (grid (32,8) = 1 round).
// Pipeline:
//   1. pack: f32 -> fp16 (q,k,v,Wq,Wk,Wv,Wo) + zero scores
//   2. gemm3 (z=3): Pq16,Pk16 = f16(A@W^T+b) [f16 out]; Pv = f32 out
//   3. scores[b,i,j] = sum_{s,c} Pq16[b,s,64i+c]*Pk16[b,s,64j+c]  (MFMA)
//   4. softmax (x0.25 scale) -> attn (d_out tail); Mm = I + beta*attn
//   5. xmix[r,64i+c] = f16( sum_j Mm[i,j]*Pv[r,64j+c] )
//   6. out = f16 GEMM(xmix, Wo^T) + bo -> d_out
// mask (d_in[3]) and adj (d_in[4]) are unused by the reference.

#define DIM 1024

typedef _Float16 f16_t;
typedef _Float16 f16x4_t __attribute__((ext_vector_type(4)));
typedef _Float16 f16x8_t __attribute__((ext_vector_type(8)));
typedef float    f32x4_t __attribute__((ext_vector_type(4)));

__device__ __forceinline__ void async_ld16(const void* g, void* l) {
    __builtin_amdgcn_global_load_lds((const __attribute__((address_space(1))) void*)g,
                                     (__attribute__((address_space(3))) void*)l,
                                     16, 0, 0);
}

// ---------------------------------------------------------------- pack kernel
// float4 units: q 2097152 | k 2097152 | v 2097152 | Wq 262144 | Wk 262144
//               | Wv 262144 | Wo 262144 => 7340032 units. Tail 16 blocks zero
//               the 4096-float scores buffer. Grid 28688 blocks.
__global__ __launch_bounds__(256) void pack_kernel(
    const float* __restrict__ q, const float* __restrict__ k, const float* __restrict__ v,
    const float* __restrict__ Wq, const float* __restrict__ Wk,
    const float* __restrict__ Wv, const float* __restrict__ Wo,
    f16_t* __restrict__ Aq, f16_t* __restrict__ Ak, f16_t* __restrict__ Av,
    f16_t* __restrict__ Bq, f16_t* __restrict__ Bk,
    f16_t* __restrict__ Bv, f16_t* __restrict__ Bo,
    float* __restrict__ scores)
{
    const int u = blockIdx.x * 256 + threadIdx.x;
    if (u >= 7340032) {            // tail: zero scores accumulator
        scores[u - 7340032] = 0.f;
        return;
    }
    const float* src; f16_t* dst; int i;
    if (u < 2097152)      { src = q;  dst = Aq; i = u; }
    else if (u < 4194304) { src = k;  dst = Ak; i = u - 2097152; }
    else if (u < 6291456) { src = v;  dst = Av; i = u - 4194304; }
    else if (u < 6553600) { src = Wq; dst = Bq; i = u - 6291456; }
    else if (u < 6815744) { src = Wk; dst = Bk; i = u - 6553600; }
    else if (u < 7077888) { src = Wv; dst = Bv; i = u - 6815744; }
    else                  { src = Wo; dst = Bo; i = u - 7077888; }
    float4 s = ((const float4*)src)[i];
    f16x4_t h;
    h[0] = (f16_t)s.x; h[1] = (f16_t)s.y; h[2] = (f16_t)s.z; h[3] = (f16_t)s.w;
    ((f16x4_t*)dst)[i] = h;
}

// --------------------------------------------- 256x128 deep-pipelined GEMM
// C[m,n] = sum_k A[m,k]*B[n,k] + bias[n]. A [M,1024] f16 rm, B [1024,1024]
// f16 rm. Tile 256x128, BK=32, 8 waves (4M x 2N), per-wave 64x64 (acc 4x4).
// LDS: 4 rotating buffers As0..3 (256x32, 16KB) + Bs0..3 (128x32, 8KB) =
// 96KB, each a DISTINCT __shared__ object so the backend proves
// ds_read(buf i) independent of in-flight global_load_lds(buf j!=i) and
// keeps our counted vmcnt (R5 post-mortem: shared-array aliasing drew
// per-phase vmcnt(0) stalls).
// Plane layout: row-major [rows][32], 16B units u=0..3 swizzled
// u' = u ^ ((row ^ row>>2)&3). Verified: ds_read_b128 frag = uniform 8
// lanes per 4-bank set (conflict-free); staging thread t writes unit t
// (+512 for A upper half): row=t>>2, global unit su=(t&3)^((t>>2^t>>4)&3);
// LDS-DMA dest = wave-uniform base + lane*16 (linear).
// Schedule per K-tile kt: {8 ds_read frags(buf kt&3); issue 3 DMA for
// kt+3 (buf (kt+3)&3); setprio(1); 16 MFMA; setprio(0); vmcnt(6);
// s_barrier}. In-flight 6-9 loads; tail drains 6->3->0; 32 barriers total.
__device__ __forceinline__ void gemm256x128_body(
    const f16_t* __restrict__ A, const f16_t* __restrict__ Bm,
    const float* __restrict__ bias, float* __restrict__ C, f16_t* __restrict__ C16,
    int tileM, int tileN)
{
    __shared__ __align__(16) f16_t As0[8192], As1[8192], As2[8192], As3[8192];
    __shared__ __align__(16) f16_t Bs0[4096], Bs1[4096], Bs2[4096], Bs3[4096];

    const int t    = threadIdx.x;
    const int lane = t & 63;
    const int w    = t >> 6;

    // staging constants (thread t -> LDS unit t, +512 for A rows 128..255)
    const int srow = t >> 2;                                   // 0..127
    const int su   = (t & 3) ^ (((t >> 2) ^ (t >> 4)) & 3);    // global 16B unit
    const f16_t* srcA = A  + (size_t)(tileM + srow) * DIM + su * 8;
    const f16_t* srcB = Bm + (size_t)(tileN + srow) * DIM + su * 8;

    // fragment-read constants
    const int lr = lane & 15;                    // frag row
    const int ku = lane >> 4;                    // frag 16B k-unit (0..3)
    const int uA = ku ^ ((lr ^ (lr >> 2)) & 3);  // swizzled unit
    const int mr = w >> 1;                       // wave M slot (0..3)
    const int nr = w & 1;                        // wave N slot (0..1)
    const int aOff = mr * 2048 + lr * 32 + uA * 8;   // + mt*512
    const int bOff = nr * 2048 + lr * 32 + uA * 8;   // + nt*512

    f32x4_t acc[4][4];
#pragma unroll
    for (int i = 0; i < 4; ++i)
#pragma unroll
        for (int j = 0; j < 4; ++j)
            acc[i][j] = (f32x4_t){0.f, 0.f, 0.f, 0.f};

#define STAGE(KT, AP, BP) do {                                              \
        const f16_t* ga_ = srcA + (KT) * 32;                                \
        async_ld16(ga_,             (void*)((AP) + (w << 9)));              \
        async_ld16(ga_ + 128 * DIM, (void*)((AP) + (w << 9) + 4096));       \
        async_ld16(srcB + (KT) * 32,(void*)((BP) + (w << 9)));              \
    } while (0)

#define ITER(KT, AP, BP, PAP, PBP) do {                                     \
        f16x8_t af_[4], bf_[4];                                             \
        _Pragma("unroll")                                                   \
        for (int mt = 0; mt < 4; ++mt)                                      \
            af_[mt] = *(const f16x8_t*)((AP) + aOff + (mt << 9));           \
        _Pragma("unroll")                                                   \
        for (int nt = 0; nt < 4; ++nt)                                      \
            bf_[nt] = *(const f16x8_t*)((BP) + bOff + (nt << 9));           \
        if ((KT) < 29) STAGE((KT) + 3, PAP, PBP);                           \
        __builtin_amdgcn_s_setprio(1);                                      \
        _Pragma("unroll")                                                   \
        for (int mt = 0; mt < 4; ++mt)                                      \
        _Pragma("unroll")                                                   \
        for (int nt = 0; nt < 4; ++nt)                                      \
            acc[mt][nt] = __builtin_amdgcn_mfma_f32_16x16x32_f16(           \
                af_[mt], bf_[nt], acc[mt][nt], 0, 0, 0);                    \
        __builtin_amdgcn_s_setprio(0);                                      \
        if ((KT) <= 28)      asm volatile("s_waitcnt vmcnt(6)" ::: "memory"); \
        else if ((KT) == 29) asm volatile("s_waitcnt vmcnt(3)" ::: "memory"); \
        else if ((KT) == 30) asm volatile("s_waitcnt vmcnt(0)" ::: "memory"); \
        if ((KT) < 31) {                                                    \
            __builtin_amdgcn_s_barrier();                                   \
            __builtin_amdgcn_sched_barrier(0);                              \
        }                                                                   \
    } while (0)

    // prologue: tiles 0,1,2 -> bufs 0,1,2 (9 loads); wait tile 0 (vmcnt 6)
    STAGE(0, As0, Bs0);
    STAGE(1, As1, Bs1);
    STAGE(2, As2, Bs2);
    asm volatile("s_waitcnt vmcnt(6)" ::: "memory");
    __builtin_amdgcn_s_barrier();
    __builtin_amdgcn_sched_barrier(0);

#define QUAD(K0)                                   \
    ITER((K0) + 0, As0, Bs0, As3, Bs3);            \
    ITER((K0) + 1, As1, Bs1, As0, Bs0);            \
    ITER((K0) + 2, As2, Bs2, As1, Bs1);            \
    ITER((K0) + 3, As3, Bs3, As2, Bs2);

    QUAD(0) QUAD(4) QUAD(8) QUAD(12) QUAD(16) QUAD(20) QUAD(24) QUAD(28)

#undef QUAD
#undef ITER
#undef STAGE

    // epilogue. C/D layout: col = lane&15, row = (lane>>4)*4 + reg
    const int rq = ku << 2;
    if (C16) {
#pragma unroll
        for (int nt = 0; nt < 4; ++nt) {
            const int col = tileN + nr * 64 + (nt << 4) + lr;
            const float bv = bias[col];
#pragma unroll
            for (int mt = 0; mt < 4; ++mt) {
                const int row = tileM + mr * 64 + (mt << 4) + rq;
#pragma unroll
                for (int r = 0; r < 4; ++r)
                    C16[(size_t)(row + r) * DIM + col] = (f16_t)(acc[mt][nt][r] + bv);
            }
        }
    } else {
#pragma unroll
        for (int nt = 0; nt < 4; ++nt) {
            const int col = tileN + nr * 64 + (nt << 4) + lr;
            const float bv = bias[col];
#pragma unroll
            for (int mt = 0; mt < 4; ++mt) {
                const int row = tileM + mr * 64 + (mt << 4) + rq;
#pragma unroll
                for (int r = 0; r < 4; ++r)
                    C[(size_t)(row + r) * DIM + col] = acc[mt][nt][r] + bv;
            }
        }
    }
}

struct Gemm3Args {
    const f16_t* A[3];
    const f16_t* B[3];
    const float* bias[3];
    float*       C[3];    // z=2 (Pv) f32 out
    f16_t*       C16[3];  // z=0,1 (Pq16, Pk16) f16 out
};

// three projection GEMMs in one launch: grid (32, 8, 3) = 768 = 3 rounds
__global__ __launch_bounds__(512, 2) void gemm3(Gemm3Args args)
{
    const int z = blockIdx.z;
    gemm256x128_body(args.A[z], args.B[z], args.bias[z], args.C[z], args.C16[z],
                     blockIdx.x * 256, blockIdx.y * 128);
}

// output projection: grid (32, 8) = 256 = 1 round, f32 out
__global__ __launch_bounds__(512, 2) void gemm_o(
    const f16_t* __restrict__ A, const f16_t* __restrict__ B,
    const float* __restrict__ bias, float* __restrict__ C)
{
    gemm256x128_body(A, B, bias, C, nullptr, blockIdx.x * 256, blockIdx.y * 128);
}

// ---------------------------------------------------------------- scores
// scores[b,i,j] = sum_n Qf[b,i,n] Kf[b,j,n], n = s*64+c. MFMA 16x16x32 per
// 32-c chunk. Grid (16 batches, 32 slices); wave w owns s = slice*16+w*4..+3.
__global__ __launch_bounds__(256) void scores_kernel(
    const f16_t* __restrict__ Pq16, const f16_t* __restrict__ Pk16,
    float* __restrict__ scores)
{
    __shared__ float red[4][256];
    const int b = blockIdx.x;
    const int lane = threadIdx.x & 63;
    const int w = threadIdx.x >> 6;
    const int m  = lane & 15;
    const int q8 = (lane >> 4) << 3;

    f32x4_t acc = (f32x4_t){0.f, 0.f, 0.f, 0.f};
    const int s0 = blockIdx.y * 16 + w * 4;
#pragma unroll
    for (int ss = 0; ss < 4; ++ss) {
        const size_t rb = (size_t)(b * 512 + s0 + ss) * DIM;
        const f16_t* qrow = Pq16 + rb;
        const f16_t* krow = Pk16 + rb;
#pragma unroll
        for (int c0 = 0; c0 < 64; c0 += 32) {
            f16x8_t af = *(const f16x8_t*)(qrow + m * 64 + c0 + q8);
            f16x8_t bf = *(const f16x8_t*)(krow + m * 64 + c0 + q8);
            acc = __builtin_amdgcn_mfma_f32_16x16x32_f16(af, bf, acc, 0, 0, 0);
        }
    }
    const int rq = (lane >> 4) << 2;
#pragma unroll
    for (int r = 0; r < 4; ++r)
        red[w][(rq + r) * 16 + m] = acc[r];
    __syncthreads();
    const int tt = threadIdx.x;
    const float sum = red[0][tt] + red[1][tt] + red[2][tt] + red[3][tt];
    atomicAdd(&scores[b * 256 + tt], sum);
}

// ---------------------------------------------------------------- softmax
__global__ __launch_bounds__(256) void softmax_kernel(
    const float* __restrict__ scores, const float* __restrict__ beta_p,
    float* __restrict__ attn_out, float* __restrict__ Mm)
{
    const int t = threadIdx.x;
    const int i = t & 15;
    const float beta = beta_p[0];
    float s[16];
    float mx = -1e30f;
#pragma unroll
    for (int j = 0; j < 16; ++j) {
        s[j] = scores[t * 16 + j] * 0.25f;
        mx = fmaxf(mx, s[j]);
    }
    float sum = 0.f;
#pragma unroll
    for (int j = 0; j < 16; ++j) { s[j] = expf(s[j] - mx); sum += s[j]; }
    const float inv = 1.f / sum;
#pragma unroll
    for (int j = 0; j < 16; ++j) {
        float a = s[j] * inv;
        attn_out[t * 16 + j] = a;
        Mm[t * 16 + j] = beta * a + ((j == i) ? 1.f : 0.f);
    }
}

// ---------------------------------------------------------------- channel mix
__global__ __launch_bounds__(256) void mix_kernel(
    const float* __restrict__ Pv, const float* __restrict__ Mm,
    f16_t* __restrict__ xmix)
{
    __shared__ float Msh[256];
    const int rbase = blockIdx.x * 8;
    const int b = rbase >> 9;
    Msh[threadIdx.x] = Mm[b * 256 + threadIdx.x];
    __syncthreads();
    const int w = threadIdx.x >> 6;
    const int lane = threadIdx.x & 63;
#pragma unroll
    for (int rr = 0; rr < 2; ++rr) {
        const int r = rbase + w * 2 + rr;
        const float* vrow = Pv + (size_t)r * DIM;
        float v[16];
#pragma unroll
        for (int j = 0; j < 16; ++j) v[j] = vrow[j * 64 + lane];
#pragma unroll
        for (int i = 0; i < 16; ++i) {
            float x = 0.f;
#pragma unroll
            for (int j = 0; j < 16; ++j) x += Msh[i * 16 + j] * v[j];
            xmix[(size_t)r * DIM + i * 64 + lane] = (f16_t)x;
        }
    }
}

// ---------------------------------------------------------------- launch
extern "C" void kernel_launch(void* const* d_in, const int* in_sizes, int n_in,
                              void* d_out, int out_size, void* d_ws, size_t ws_size,
                              hipStream_t stream)
{
    (void)in_sizes; (void)n_in; (void)out_size; (void)ws_size;
    const float* q    = (const float*)d_in[0];
    const float* k    = (const float*)d_in[1];
    const float* v    = (const float*)d_in[2];
    // d_in[3] mask, d_in[4] adj: unused by reference
    const float* Wq   = (const float*)d_in[5];
    const float* bq   = (const float*)d_in[6];
    const float* Wk   = (const float*)d_in[7];
    const float* bk   = (const float*)d_in[8];
    const float* Wv   = (const float*)d_in[9];
    const float* bv   = (const float*)d_in[10];
    const float* Wo   = (const float*)d_in[11];
    const float* bo   = (const float*)d_in[12];
    const float* beta = (const float*)d_in[13];

    float* out  = (float*)d_out;                     // [8192,1024]
    float* attn = (float*)d_out + 8388608;           // [16,16,16]

    char* p = (char*)d_ws;
    auto take = [&](size_t n) -> char* {
        char* cur = p; p += (n + 255) & ~(size_t)255; return cur;
    };
    f16_t* Aq = (f16_t*)take(16777216);
    f16_t* Ak = (f16_t*)take(16777216);
    f16_t* Av = (f16_t*)take(16777216);
    f16_t* Bq = (f16_t*)take(2097152);
    f16_t* Bk = (f16_t*)take(2097152);
    f16_t* Bv = (f16_t*)take(2097152);
    f16_t* Bo = (f16_t*)take(2097152);
    f16_t* Pq16 = (f16_t*)take(16777216);
    f16_t* Pk16 = (f16_t*)take(16777216);
    float* Pv = (float*)take(33554432);
    float* scores = (float*)take(16384);
    float* Mm     = (float*)take(16384);
    f16_t* xmix = Aq;  // Aq dead after gemm3; reuse for xmix

    pack_kernel<<<28688, 256, 0, stream>>>(q, k, v, Wq, Wk, Wv, Wo,
                                           Aq, Ak, Av, Bq, Bk, Bv, Bo, scores);

    Gemm3Args ga;
    ga.A[0] = Aq; ga.A[1] = Ak; ga.A[2] = Av;
    ga.B[0] = Bq; ga.B[1] = Bk; ga.B[2] = Bv;
    ga.bias[0] = bq; ga.bias[1] = bk; ga.bias[2] = bv;
    ga.C[0] = nullptr; ga.C[1] = nullptr; ga.C[2] = Pv;
    ga.C16[0] = Pq16; ga.C16[1] = Pk16; ga.C16[2] = nullptr;
    gemm3<<<dim3(32, 8, 3), 512, 0, stream>>>(ga);

    scores_kernel<<<dim3(16, 32), 256, 0, stream>>>(Pq16, Pk16, scores);
    softmax_kernel<<<1, 256, 0, stream>>>(scores, beta, attn, Mm);
    mix_kernel<<<1024, 256, 0, stream>>>(Pv, Mm, xmix);
    gemm_o<<<dim3(32, 8), 512, 0, stream>>>(xmix, Bo, bo, out);
}